// Round 2
// baseline (933.843 us; speedup 1.0000x reference)
//
#include <hip/hip_runtime.h>
#include <math.h>

#define N_NODES 100000
#define N_EDGES 3200000
#define SCAN_BLOCKS 391          // ceil(N_NODES/256)

// ---------------------------------------------------------------------------
// gemm1: h[N,16] = x[N,512] @ W1[512,16]   (unchanged from R1)
// ---------------------------------------------------------------------------
__global__ __launch_bounds__(256) void gemm1_kernel(
    const float* __restrict__ x, const float* __restrict__ W1,
    float* __restrict__ h, int nrows)
{
    __shared__ float xs[32 * 260];
    const int t = threadIdx.x;
    const int rbase = blockIdx.x * 256;
    const int rq = t >> 2;
    const int cg = t & 3;

    float4 acc0 = make_float4(0.f, 0.f, 0.f, 0.f);
    float4 acc1 = acc0, acc2 = acc0, acc3 = acc0;

    const int kl4  = (t & 7) * 4;
    const int rstg = t >> 3;
    const float4* w4 = (const float4*)W1;

    for (int kc = 0; kc < 512; kc += 32) {
        #pragma unroll
        for (int i = 0; i < 8; ++i) {
            int row = rstg + i * 32;
            int rg  = rbase + row;
            float4 v = make_float4(0.f, 0.f, 0.f, 0.f);
            if (rg < nrows)
                v = *(const float4*)(x + (size_t)rg * 512 + kc + kl4);
            xs[(kl4 + 0) * 260 + row] = v.x;
            xs[(kl4 + 1) * 260 + row] = v.y;
            xs[(kl4 + 2) * 260 + row] = v.z;
            xs[(kl4 + 3) * 260 + row] = v.w;
        }
        __syncthreads();

        #pragma unroll
        for (int k4 = 0; k4 < 8; ++k4) {
            const int k0 = k4 * 4;
            float4 xv0 = *(const float4*)(xs + (k0 + 0) * 260 + rq * 4);
            float4 xv1 = *(const float4*)(xs + (k0 + 1) * 260 + rq * 4);
            float4 xv2 = *(const float4*)(xs + (k0 + 2) * 260 + rq * 4);
            float4 xv3 = *(const float4*)(xs + (k0 + 3) * 260 + rq * 4);
            float4 wv0 = w4[(kc + k0 + 0) * 4 + cg];
            float4 wv1 = w4[(kc + k0 + 1) * 4 + cg];
            float4 wv2 = w4[(kc + k0 + 2) * 4 + cg];
            float4 wv3 = w4[(kc + k0 + 3) * 4 + cg];

            #define GCN_UPD(xv, wv)                                           \
                acc0.x += (xv).x * (wv).x; acc0.y += (xv).x * (wv).y;         \
                acc0.z += (xv).x * (wv).z; acc0.w += (xv).x * (wv).w;         \
                acc1.x += (xv).y * (wv).x; acc1.y += (xv).y * (wv).y;         \
                acc1.z += (xv).y * (wv).z; acc1.w += (xv).y * (wv).w;         \
                acc2.x += (xv).z * (wv).x; acc2.y += (xv).z * (wv).y;         \
                acc2.z += (xv).z * (wv).z; acc2.w += (xv).z * (wv).w;         \
                acc3.x += (xv).w * (wv).x; acc3.y += (xv).w * (wv).y;         \
                acc3.z += (xv).w * (wv).z; acc3.w += (xv).w * (wv).w;
            GCN_UPD(xv0, wv0)
            GCN_UPD(xv1, wv1)
            GCN_UPD(xv2, wv2)
            GCN_UPD(xv3, wv3)
            #undef GCN_UPD
        }
        __syncthreads();
    }
    {
        int rg = rbase + rq * 4;
        if (rg + 0 < nrows) *(float4*)(h + (size_t)(rg + 0) * 16 + cg * 4) = acc0;
        if (rg + 1 < nrows) *(float4*)(h + (size_t)(rg + 1) * 16 + cg * 4) = acc1;
        if (rg + 2 < nrows) *(float4*)(h + (size_t)(rg + 2) * 16 + cg * 4) = acc2;
        if (rg + 3 < nrows) *(float4*)(h + (size_t)(rg + 3) * 16 + cg * 4) = acc3;
    }
}

// ---------------------------------------------------------------------------
// CSR build: histogram -> 3-kernel exclusive scan -> atomic slot fill
// ---------------------------------------------------------------------------
__global__ __launch_bounds__(256) void hist_kernel(
    const int* __restrict__ ei, int* __restrict__ deg)
{
    int e = blockIdx.x * 256 + threadIdx.x;
    if (e >= N_EDGES) return;
    atomicAdd(deg + ei[N_EDGES + e], 1);
}

__global__ __launch_bounds__(256) void scan1_kernel(
    const int* __restrict__ deg, int* __restrict__ partial)
{
    __shared__ int s[256];
    int t = threadIdx.x;
    int i = blockIdx.x * 256 + t;
    s[t] = (i < N_NODES) ? deg[i] : 0;
    __syncthreads();
    for (int off = 128; off > 0; off >>= 1) {
        if (t < off) s[t] += s[t + off];
        __syncthreads();
    }
    if (t == 0) partial[blockIdx.x] = s[0];
}

__global__ __launch_bounds__(512) void scan2_kernel(int* __restrict__ partial)
{
    __shared__ int s[512];
    int t = threadIdx.x;
    s[t] = (t < SCAN_BLOCKS) ? partial[t] : 0;
    __syncthreads();
    for (int off = 1; off < 512; off <<= 1) {
        int v = (t >= off) ? s[t - off] : 0;
        __syncthreads();
        s[t] += v;
        __syncthreads();
    }
    if (t < SCAN_BLOCKS) partial[t] = (t == 0) ? 0 : s[t - 1];  // exclusive
}

__global__ __launch_bounds__(256) void scan3_kernel(
    const int* __restrict__ deg, const int* __restrict__ partial,
    int* __restrict__ row_ptr, int* __restrict__ cursor)
{
    __shared__ int s[256];
    int t = threadIdx.x;
    int i = blockIdx.x * 256 + t;
    int v = (i < N_NODES) ? deg[i] : 0;
    s[t] = v;
    __syncthreads();
    for (int off = 1; off < 256; off <<= 1) {
        int u = (t >= off) ? s[t - off] : 0;
        __syncthreads();
        s[t] += u;
        __syncthreads();
    }
    int base = partial[blockIdx.x];
    int excl = base + ((t == 0) ? 0 : s[t - 1]);
    if (i < N_NODES) {
        row_ptr[i] = excl;
        cursor[i]  = excl;
        if (i == N_NODES - 1) row_ptr[N_NODES] = base + s[t];
    }
}

__global__ __launch_bounds__(256) void fill_kernel(
    const int* __restrict__ ei, int* __restrict__ cursor,
    int* __restrict__ csr_src)
{
    int e = blockIdx.x * 256 + threadIdx.x;
    if (e >= N_EDGES) return;
    int s = ei[e];
    int d = ei[N_EDGES + e];
    int pos = atomicAdd(cursor + d, 1);
    csr_src[pos] = s;
}

// ---------------------------------------------------------------------------
// gather1: one wave per node. 64 lanes = 4 edges x 16 channels per iter.
// acc reduced across the 4 edge-quadrants via shfl_xor. Fused +b1, relu.
// ---------------------------------------------------------------------------
__global__ __launch_bounds__(256) void gather1_kernel(
    const int* __restrict__ row_ptr, const int* __restrict__ csr_src,
    const float* __restrict__ h, const float* __restrict__ b1,
    float* __restrict__ h1)
{
    int node = (blockIdx.x * 256 + threadIdx.x) >> 6;
    if (node >= N_NODES) return;
    int lane = threadIdx.x & 63;
    int c = lane & 15, q = lane >> 4;
    int start = row_ptr[node], end = row_ptr[node + 1];
    float acc = 0.f;
    for (int p = start + q; p < end; p += 4) {
        int s = csr_src[p];
        acc += h[(size_t)s * 16 + c];
    }
    acc += __shfl_xor(acc, 16);
    acc += __shfl_xor(acc, 32);
    if (lane < 16)
        h1[(size_t)node * 16 + c] = fmaxf(acc + b1[c], 0.f);
}

// gather2: same, writes raw aggregation (W2/b2/log_softmax applied after)
__global__ __launch_bounds__(256) void gather2_kernel(
    const int* __restrict__ row_ptr, const int* __restrict__ csr_src,
    const float* __restrict__ h1, float* __restrict__ agg2)
{
    int node = (blockIdx.x * 256 + threadIdx.x) >> 6;
    if (node >= N_NODES) return;
    int lane = threadIdx.x & 63;
    int c = lane & 15, q = lane >> 4;
    int start = row_ptr[node], end = row_ptr[node + 1];
    float acc = 0.f;
    for (int p = start + q; p < end; p += 4) {
        int s = csr_src[p];
        acc += h1[(size_t)s * 16 + c];
    }
    acc += __shfl_xor(acc, 16);
    acc += __shfl_xor(acc, 32);
    if (lane < 16)
        agg2[(size_t)node * 16 + c] = acc;
}

// ---------------------------------------------------------------------------
// gemm2 + bias + log_softmax fused (unchanged from R1)
// ---------------------------------------------------------------------------
__global__ __launch_bounds__(256) void gemm2_lsm_kernel(
    const float* __restrict__ agg2, const float* __restrict__ W2,
    const float* __restrict__ b2, float* __restrict__ out, int nrows)
{
    __shared__ float4 w2s[160];
    __shared__ float4 b2s[10];
    const int t = threadIdx.x;
    if (t < 160) w2s[t] = ((const float4*)W2)[t];
    else if (t < 170) b2s[t - 160] = ((const float4*)b2)[t - 160];
    __syncthreads();

    const int row = blockIdx.x * 256 + t;
    if (row >= nrows) return;

    float a[16];
    {
        const float4* ap = (const float4*)(agg2 + (size_t)row * 16);
        float4 a0 = ap[0], a1 = ap[1], a2 = ap[2], a3 = ap[3];
        a[0]=a0.x; a[1]=a0.y; a[2]=a0.z; a[3]=a0.w;
        a[4]=a1.x; a[5]=a1.y; a[6]=a1.z; a[7]=a1.w;
        a[8]=a2.x; a[9]=a2.y; a[10]=a2.z; a[11]=a2.w;
        a[12]=a3.x; a[13]=a3.y; a[14]=a3.z; a[15]=a3.w;
    }

    float4 z[10];
    #pragma unroll
    for (int c4 = 0; c4 < 10; ++c4) z[c4] = b2s[c4];

    #pragma unroll
    for (int k = 0; k < 16; ++k) {
        const float av = a[k];
        #pragma unroll
        for (int c4 = 0; c4 < 10; ++c4) {
            float4 w = w2s[k * 10 + c4];
            z[c4].x += av * w.x;
            z[c4].y += av * w.y;
            z[c4].z += av * w.z;
            z[c4].w += av * w.w;
        }
    }

    float m = z[0].x;
    #pragma unroll
    for (int c4 = 0; c4 < 10; ++c4) {
        m = fmaxf(m, z[c4].x); m = fmaxf(m, z[c4].y);
        m = fmaxf(m, z[c4].z); m = fmaxf(m, z[c4].w);
    }
    float s = 0.f;
    #pragma unroll
    for (int c4 = 0; c4 < 10; ++c4) {
        s += __expf(z[c4].x - m); s += __expf(z[c4].y - m);
        s += __expf(z[c4].z - m); s += __expf(z[c4].w - m);
    }
    const float lse = m + __logf(s);

    float4* op = (float4*)(out + (size_t)row * 40);
    #pragma unroll
    for (int c4 = 0; c4 < 10; ++c4) {
        float4 o;
        o.x = z[c4].x - lse; o.y = z[c4].y - lse;
        o.z = z[c4].z - lse; o.w = z[c4].w - lse;
        op[c4] = o;
    }
}

// ---------------------------------------------------------------------------
extern "C" void kernel_launch(void* const* d_in, const int* in_sizes, int n_in,
                              void* d_out, int out_size, void* d_ws, size_t ws_size,
                              hipStream_t stream)
{
    const float* x  = (const float*)d_in[0];
    const int*   ei = (const int*)d_in[1];
    const float* W1 = (const float*)d_in[2];
    const float* b1 = (const float*)d_in[3];
    const float* W2 = (const float*)d_in[4];
    const float* b2 = (const float*)d_in[5];
    float* out = (float*)d_out;

    // ws layout (floats/ints, ~27 MB total):
    //   h    : N*16 f32 (6.4MB)   -- also reused as agg2 after gather1
    //   h1   : N*16 f32 (6.4MB)
    //   csr  : E int   (12.8MB)
    //   deg  : N int   (400KB)
    //   rowp : N+1 int (400KB)
    //   curs : N int   (400KB)
    //   part : SCAN_BLOCKS int
    float* h    = (float*)d_ws;
    float* h1   = h + (size_t)N_NODES * 16;
    int*   csr  = (int*)(h1 + (size_t)N_NODES * 16);
    int*   deg  = csr + N_EDGES;
    int*   rowp = deg + N_NODES;
    int*   curs = rowp + (N_NODES + 1);
    int*   part = curs + N_NODES;
    float* agg2 = h;   // h is dead after gather1

    const int edge_blocks = (N_EDGES + 255) / 256;   // 12500
    const int node_blocks = (N_NODES + 255) / 256;   // 391
    const int wave_blocks = (N_NODES + 3) / 4;       // 25000 (4 waves/block)

    // --- CSR build (independent of gemm1) ---
    hipMemsetAsync(deg, 0, N_NODES * sizeof(int), stream);
    hist_kernel <<<edge_blocks, 256, 0, stream>>>(ei, deg);
    scan1_kernel<<<SCAN_BLOCKS, 256, 0, stream>>>(deg, part);
    scan2_kernel<<<1, 512, 0, stream>>>(part);
    scan3_kernel<<<SCAN_BLOCKS, 256, 0, stream>>>(deg, part, rowp, curs);
    fill_kernel <<<edge_blocks, 256, 0, stream>>>(ei, curs, csr);

    // --- conv1 ---
    gemm1_kernel  <<<node_blocks, 256, 0, stream>>>(x, W1, h, N_NODES);
    gather1_kernel<<<wave_blocks, 256, 0, stream>>>(rowp, csr, h, b1, h1);

    // --- conv2 + log_softmax ---
    gather2_kernel<<<wave_blocks, 256, 0, stream>>>(rowp, csr, h1, agg2);
    gemm2_lsm_kernel<<<node_blocks, 256, 0, stream>>>(agg2, W2, b2, out, N_NODES);
}